// Round 8
// baseline (175.038 us; speedup 1.0000x reference)
//
#include <hip/hip_runtime.h>
#include <math.h>

#define W 512
#define H 512
#define NUM_R 725
#define NUM_T 180
#define RCHUNK 64               // sweep-rows per block
#define NCHUNK (H / RCHUNK)     // 8
#define RPAD 768                // padded rho bins

// ws layout: [0, W*H) floats = imgT ; then NCHUNK*NUM_T*RPAD floats = partials
#define WS_FLOATS ((size_t)W * H + (size_t)NCHUNK * NUM_T * RPAD)

// ---------------------------------------------------------------------------
// Transpose 512x512 f32: imgT[a*H + b] = img[b*W + a]
// ---------------------------------------------------------------------------
__global__ __launch_bounds__(256) void transpose_k(const float* __restrict__ in,
                                                   float* __restrict__ out) {
    __shared__ float tile[32][33];
    const int bx = blockIdx.x * 32, by = blockIdx.y * 32;
    const int tx = threadIdx.x, ty = threadIdx.y;  // block (32, 8)
#pragma unroll
    for (int j = 0; j < 32; j += 8)
        tile[ty + j][tx] = in[(size_t)(by + ty + j) * W + (bx + tx)];
    __syncthreads();
#pragma unroll
    for (int j = 0; j < 32; j += 8)
        out[(size_t)(bx + ty + j) * H + (by + tx)] = tile[tx][ty + j];
}

// ---------------------------------------------------------------------------
// Scatter Hough with native LDS fp atomics (ds_add_f32 via unsafeAtomicAdd).
// Lane axis = max(|s|,|c|) axis. Pixel hits bin r iff |u - r| <= hw,
//   u = (i*c + j*s + diag)/step, hw = max(|s|,|c|)/(2*step)
// — algebraically identical to the reference's round() membership.
// Window tiling (2hw = lane pixel spacing) keeps same-iteration hits in
// distinct bins; HW atomicity covers all residual cross-wave collisions, so a
// single shared racc[768] (3 KB) suffices. One fire-and-forget ds op per hit
// slot: no read-latency chain, half the ds issue count of the explicit RMW.
// Q32 incremental u, f64 refresh per block (validated R4-R7: absmax 2.0).
//   waves 0,1 -> row n0+2j ; waves 2,3 -> row n0+2j+1.
// ---------------------------------------------------------------------------
__global__ __launch_bounds__(256) void hough_scatter_k(const float* __restrict__ img,
                                                       const float* __restrict__ imgT,
                                                       float* __restrict__ partial) {
    const int t   = blockIdx.x;            // theta 0..179
    const int n0  = blockIdx.y * RCHUNK;   // sweep-row chunk base
    const int tid = threadIdx.x;

    __shared__ float racc[RPAD];           // shared bin accumulators (3 KB)

    racc[tid] = 0.f;
    racc[tid + 256] = 0.f;
    racc[tid + 512] = 0.f;
    __syncthreads();

    // ---- per-theta constants (f64, same trig path validated R1-R7) ----
    const double theta = (double)t * (M_PI / 180.0);
    const double s = sin(theta);
    const double c = cos(theta);
    const bool use_x = fabs(s) >= fabs(c);
    const double diag = sqrt(524288.0);          // sqrt(W*W + H*H)
    const double step = (2.0 * diag) / 724.0;    // np.linspace step
    const double inv_step = 1.0 / step;

    const double lane_co = (use_x ? s : c) * inv_step;  // du per pixel (lane axis)
    const double loop_co = (use_x ? c : s) * inv_step;  // du per sweep row
    const double dstep   = diag * inv_step;

    const double SC = 4294967296.0;              // 2^32
    const long long laneq = (long long)rint(lane_co * SC);
    const long long lq    = (long long)rint(loop_co * SC);
    const long long lq2   = 2 * lq;              // u advance per iteration (2 rows)
    const long long L1 = laneq, L2 = 2 * laneq, L3 = 3 * laneq;
    const unsigned hwq = (unsigned)(fabs(lane_co) * 0.5 * SC);
    const unsigned A = 0x80000000u - hwq;        // hit iff lo32 - A <= B
    const unsigned B = 2u * hwq;

    // ---- this thread's 4 lane-axis pixels on row-half h ----
    const int h  = tid >> 7;                     // 0: even rows, 1: odd rows
    const int c0 = (tid & 127) * 4;              // column base
    const double rowpart = (double)(n0 + h) * loop_co + dstep;
    long long u = (long long)rint((rowpart + (double)c0 * lane_co) * SC) + (1ll << 31);

    const float* __restrict__ base = use_x ? img : imgT;
    const float4* rowp = (const float4*)(base + (size_t)(n0 + h) * W) + (tid & 127);

#pragma unroll 4
    for (int j = 0; j < RCHUNK / 2; ++j) {
        const float4 v = rowp[j * (2 * W / 4)];
        const long long u0 = u;
        const long long u1 = u + L1;
        const long long u2 = u + L2;
        const long long u3 = u + L3;
        u += lq2;
        // native ds_add_f32, fire-and-forget: no CAS loop, no RAW chain
        if ((unsigned)u0 - A <= B) unsafeAtomicAdd(&racc[(int)(u0 >> 32)], v.x);
        if ((unsigned)u1 - A <= B) unsafeAtomicAdd(&racc[(int)(u1 >> 32)], v.y);
        if ((unsigned)u2 - A <= B) unsafeAtomicAdd(&racc[(int)(u2 >> 32)], v.z);
        if ((unsigned)u3 - A <= B) unsafeAtomicAdd(&racc[(int)(u3 >> 32)], v.w);
    }

    __syncthreads();

    // ---- non-atomic flush: partial[chunk][t][r] (coalesced) ----
    float* dst = partial + ((size_t)blockIdx.y * NUM_T + t) * RPAD;
    dst[tid]       = racc[tid];
    dst[tid + 256] = racc[tid + 256];
    dst[tid + 512] = racc[tid + 512];
}

// ---------------------------------------------------------------------------
// Sum the NCHUNK partials into out[r*NUM_T + t]. Block = one theta.
// ---------------------------------------------------------------------------
__global__ __launch_bounds__(256) void reduce_k(const float* __restrict__ partial,
                                                float* __restrict__ out) {
    const int t = blockIdx.x;
    const int tid = threadIdx.x;
#pragma unroll
    for (int k = 0; k < 3; ++k) {
        const int r = tid + 256 * k;
        if (r < NUM_R) {
            float acc = 0.f;
#pragma unroll
            for (int ch = 0; ch < NCHUNK; ++ch)
                acc += partial[((size_t)ch * NUM_T + t) * RPAD + r];
            out[(size_t)r * NUM_T + t] = acc;
        }
    }
}

// ---------------------------------------------------------------------------
// Fallback (ws too small): R3's pure-gather kernel, no ws, no atomics.
// ---------------------------------------------------------------------------
__global__ __launch_bounds__(256) void hough_gather_k(const float* __restrict__ img,
                                                      float* __restrict__ out) {
    const int t = blockIdx.x;
    const int r = blockIdx.y * 256 + threadIdx.x;
    const int rc = (r < NUM_R) ? r : (NUM_R - 1);

    const double theta = (double)t * (M_PI / 180.0);
    const double s = sin(theta);
    const double c = cos(theta);
    const bool use_x = fabs(s) >= fabs(c);
    double dd = use_x ? s : c;
    if (fabs(dd) < 1e-6) dd = 1.0;
    const double a = use_x ? c : s;
    const double inv = 1.0 / dd;
    const double nk2 = -(a * inv);
    const double diag = sqrt(524288.0);
    const double step = (2.0 * diag) / 724.0;
    double rho = (double)rc * step - diag;
    if (rc == NUM_R - 1) rho = diag;

    const double SCALE = 1099511627776.0;  // 2^40
    const long long NK2q = (long long)rint(nk2 * SCALE);
    long long Y = (long long)rint(rho * inv * SCALE) + (1ll << 39);

    float acc = 0.f;
    if (use_x) {
#pragma unroll 8
        for (int n = 0; n < W; ++n) {
            const int y = (int)(Y >> 40);
            Y += NK2q;
            const float v = img[n * W + min(max(y, 0), W - 1)];
            acc += ((unsigned)y < (unsigned)W) ? v : 0.f;
        }
    } else {
#pragma unroll 4
        for (int n = 0; n < W; ++n) {
            const int y = (int)(Y >> 40);
            Y += NK2q;
            const float v = img[min(max(y, 0), W - 1) * W + n];
            acc += ((unsigned)y < (unsigned)W) ? v : 0.f;
        }
    }
    if (r < NUM_R) out[(size_t)r * NUM_T + t] = acc;
}

extern "C" void kernel_launch(void* const* d_in, const int* in_sizes, int n_in,
                              void* d_out, int out_size, void* d_ws, size_t ws_size,
                              hipStream_t stream) {
    const float* img = (const float*)d_in[0];
    float* out = (float*)d_out;

    if (ws_size >= WS_FLOATS * sizeof(float)) {
        float* imgT = (float*)d_ws;
        float* partial = (float*)d_ws + (size_t)W * H;

        transpose_k<<<dim3(16, 16), dim3(32, 8), 0, stream>>>(img, imgT);
        hough_scatter_k<<<dim3(NUM_T, NCHUNK), dim3(256), 0, stream>>>(img, imgT, partial);
        reduce_k<<<dim3(NUM_T), dim3(256), 0, stream>>>(partial, out);
    } else {
        hough_gather_k<<<dim3(NUM_T, (NUM_R + 255) / 256), dim3(256), 0, stream>>>(img, out);
    }
}